// Round 4
// baseline (175.544 us; speedup 1.0000x reference)
//
#include <hip/hip_runtime.h>
#include <stdint.h>

// MemoryEfficientBSpline: out[b,o,p] = sum_i sum_g hat_g(nx[b,i,p]) * coef[b,o,i,g]
// hat_g(nx) = max(0, 1 - |nx - g|), nx = (clamp(x,-1,1)+1)*2.5 in [0,5], G=6.
// Batched GEMM via mfma_f32_16x16x32_f16 with OPERANDS: A = hat-weights (p x k),
// B = coef (k x o)  =>  D rows = p (4 consecutive p per lane -> dwordx4 stores).
// NO LDS, NO BARRIERS: each lane loads exactly the x values its fragments need
// (fixed (pti,j): 4 i-rows x 64B fully-consumed lines), waves fully independent.
// coef is pre-swizzled once (prep kernel) to f16 hardware-k order, L2-resident.

typedef __fp16 half8_t __attribute__((ext_vector_type(8)));
typedef __fp16 half2_t __attribute__((ext_vector_type(2)));
typedef float f32x4 __attribute__((ext_vector_type(4)));

#define NBATCH 8
#define OD 64
#define ID 64
#define PIX 36864          // 192*192
#define NG 6
#define PT 192             // pixels per block tile (48 per wave)
#define KI 32              // i per chunk
#define NCHUNK 2
#define KROW 384           // k extent per (b,o) row in cpre
#define PTILES (PIX / PT)  // 192

#define CPRE_BYTES (NBATCH * OD * KROW * 2)  // 393216

__global__ __launch_bounds__(256)
void prep_coef(const float* __restrict__ coef, __fp16* __restrict__ cpre) {
  int idx = blockIdx.x * 256 + threadIdx.x;  // 0 .. 196607
  int b = idx / (OD * KROW);
  int rem = idx % (OD * KROW);
  int o = rem / KROW;
  int k = rem % KROW;
  int c = k / 192;
  int s = k % 192;
  int g = s >> 5;          // slot s = ks*32 + iof  <->  g = ks, iof = s&31
  int iof = s & 31;
  float v = coef[((size_t)(b * OD + o) * ID + c * KI + iof) * NG + g];
  cpre[idx] = (__fp16)v;   // writes coalesced
}

__global__ __launch_bounds__(256, 4)
void kan_mfma3(const float* __restrict__ x, const __fp16* __restrict__ cpre,
               float* __restrict__ out) {
  const int t = threadIdx.x;
  const int lane = t & 63;
  const int wave = t >> 6;   // p sub-range [wave*48, wave*48+48)
  const int q8 = lane >> 4;
  const int col = lane & 15;

  const int b = blockIdx.x / PTILES;
  const int pw = (blockIdx.x % PTILES) * PT + wave * 48;

  f32x4 acc[4][3];  // [ot(o-tile)][pti(p-subtile)]
#pragma unroll
  for (int i = 0; i < 4; ++i)
#pragma unroll
    for (int j = 0; j < 3; ++j)
      acc[i][j] = (f32x4){0.f, 0.f, 0.f, 0.f};

  const float* xb = x + (size_t)b * ID * PIX + pw + col;
  const __fp16* cb = cpre + (size_t)b * OD * KROW + q8 * 8;

#pragma unroll
  for (int c = 0; c < NCHUNK; ++c) {
    // ---- per-lane nx: i = c*32 + q8*8 + j, p = pw + pti*16 + col ----
    // per load instr (pti,j): 4 i-rows x 64B contiguous -> full-line coalesced
    float nxv[3][8];
#pragma unroll
    for (int pti = 0; pti < 3; ++pti)
#pragma unroll
      for (int j = 0; j < 8; ++j) {
        float xv = xb[(size_t)(c * KI + q8 * 8 + j) * PIX + pti * 16];
        xv = fminf(fmaxf(xv, -1.f), 1.f);
        nxv[pti][j] = (xv + 1.f) * 2.5f;
      }

    const __fp16* cc = cb + c * 192;
#pragma unroll
    for (int ks = 0; ks < 6; ++ks) {  // g = ks
      half8_t bf[4];  // B-fragment: coef[k = q8*8+j][o = ot*16+col]
#pragma unroll
      for (int ot = 0; ot < 4; ++ot)
        bf[ot] = *(const half8_t*)(cc + (size_t)(ot * 16 + col) * KROW + ks * 32);

      const float gf = (float)ks;
#pragma unroll
      for (int pti = 0; pti < 3; ++pti) {
        union { half2_t h2[4]; half8_t v; } au;  // A-frag: hat(nx[k-slot]) at my p
#pragma unroll
        for (int jj = 0; jj < 4; ++jj) {
          float h0 = fmaxf(0.f, 1.f - fabsf(nxv[pti][2 * jj] - gf));
          float h1 = fmaxf(0.f, 1.f - fabsf(nxv[pti][2 * jj + 1] - gf));
          au.h2[jj] = __builtin_amdgcn_cvt_pkrtz(h0, h1);
        }
#pragma unroll
        for (int ot = 0; ot < 4; ++ot)
          acc[ot][pti] = __builtin_amdgcn_mfma_f32_16x16x32_f16(
              au.v, bf[ot], acc[ot][pti], 0, 0, 0);
      }
    }
  }

  // ---- epilogue: D row = p (q8*4 + r), col = o. 4 consecutive p per lane ----
  // per store instr: 16 o-rows x 64B contiguous -> 1KB full lines
  float* ob = out + (size_t)b * OD * PIX + pw + q8 * 4;
#pragma unroll
  for (int ot = 0; ot < 4; ++ot)
#pragma unroll
    for (int pti = 0; pti < 3; ++pti)
      *(f32x4*)(ob + (size_t)(ot * 16 + col) * PIX + pti * 16) = acc[ot][pti];
}

// ---------- fallback (proven R2 kernel) if ws too small for cpre ----------
#define AROW 104
#define XROW 18
__global__ __launch_bounds__(256, 2)
void kan_mfma_fb(const float* __restrict__ x, const float* __restrict__ coef,
                 float* __restrict__ out) {
  const int t = threadIdx.x;
  const int lane = t & 63;
  const int wave = t >> 6;
  const int q8 = lane >> 4;
  const int col = lane & 15;
  const int bid = blockIdx.x;
  const int b = bid / PTILES;
  const int p0 = (bid % PTILES) * PT;

  __shared__ __fp16 A_lds[OD][AROW] __attribute__((aligned(16)));
  __shared__ float nxf[PT][XROW] __attribute__((aligned(16)));

  f32x4 acc[4][3];
#pragma unroll
  for (int i = 0; i < 4; ++i)
#pragma unroll
    for (int j = 0; j < 3; ++j) acc[i][j] = (f32x4){0.f, 0.f, 0.f, 0.f};

  const float* xb = x + (size_t)b * ID * PIX + p0;
  const float* cb = coef + (size_t)b * OD * ID * NG;
  const int iof0 = (q8 & 1) * 8;
  const int ghalf = q8 >> 1;

  for (int c = 0; c < 4; ++c) {
    const int i0 = c * 16;
    __syncthreads();
#pragma unroll
    for (int j = 0; j < 12; ++j) {
      int lin = j * 256 + t;
      int p = lin % PT;
      int iof = lin / PT;
      float xvv = xb[(size_t)(i0 + iof) * PIX + p];
      xvv = fminf(fmaxf(xvv, -1.f), 1.f);
      nxf[p][iof] = (xvv + 1.f) * 2.5f;
    }
    {
      const int o = t >> 2;
      const int r0 = (t & 3) * 24;
      const float* crow = cb + o * (ID * NG) + i0 * NG + r0;
#pragma unroll
      for (int j = 0; j < 24; ++j) {
        int r = r0 + j;
        int iof = r / 6;
        int g = r - iof * 6;
        A_lds[o][g * 16 + iof] = (__fp16)crow[j];
      }
    }
    __syncthreads();

    float nxv[3][8];
#pragma unroll
    for (int pti = 0; pti < 3; ++pti) {
      int p = wave * 48 + pti * 16 + col;
#pragma unroll
      for (int j = 0; j < 8; ++j) nxv[pti][j] = nxf[p][iof0 + j];
    }
#pragma unroll
    for (int ks = 0; ks < 3; ++ks) {
      half8_t af[4];
#pragma unroll
      for (int ot = 0; ot < 4; ++ot)
        af[ot] = *(const half8_t*)&A_lds[ot * 16 + col][ks * 32 + q8 * 8];
      const float gf = (float)(2 * ks + ghalf);
#pragma unroll
      for (int pti = 0; pti < 3; ++pti) {
        union { half2_t h2[4]; half8_t v; } bu;
#pragma unroll
        for (int jj = 0; jj < 4; ++jj) {
          float h0 = fmaxf(0.f, 1.f - fabsf(nxv[pti][2 * jj] - gf));
          float h1 = fmaxf(0.f, 1.f - fabsf(nxv[pti][2 * jj + 1] - gf));
          bu.h2[jj] = __builtin_amdgcn_cvt_pkrtz(h0, h1);
        }
#pragma unroll
        for (int ot = 0; ot < 4; ++ot)
          acc[ot][pti] = __builtin_amdgcn_mfma_f32_16x16x32_f16(
              af[ot], bu.v, acc[ot][pti], 0, 0, 0);
      }
    }
  }
  float* ob = out + (size_t)b * OD * PIX + p0;
#pragma unroll
  for (int ot = 0; ot < 4; ++ot)
#pragma unroll
    for (int pti = 0; pti < 3; ++pti) {
      int p = wave * 48 + pti * 16 + col;
#pragma unroll
      for (int r = 0; r < 4; ++r)
        ob[(size_t)(ot * 16 + q8 * 4 + r) * PIX + p] = acc[ot][pti][r];
    }
}

extern "C" void kernel_launch(void* const* d_in, const int* in_sizes, int n_in,
                              void* d_out, int out_size, void* d_ws, size_t ws_size,
                              hipStream_t stream) {
  const float* x = (const float*)d_in[0];
  const float* coef = (const float*)d_in[1];
  float* out = (float*)d_out;
  if (ws_size >= (size_t)CPRE_BYTES) {
    __fp16* cpre = (__fp16*)d_ws;
    hipLaunchKernelGGL(prep_coef, dim3((NBATCH * OD * KROW) / 256), dim3(256), 0,
                       stream, coef, cpre);
    hipLaunchKernelGGL(kan_mfma3, dim3(NBATCH * PTILES), dim3(256), 0, stream, x,
                       cpre, out);
  } else {
    hipLaunchKernelGGL(kan_mfma_fb, dim3(NBATCH * PTILES), dim3(256), 0, stream,
                       x, coef, out);
  }
}

// Round 5
// 163.982 us; speedup vs baseline: 1.0705x; 1.0705x over previous
//
#include <hip/hip_runtime.h>
#include <stdint.h>

// MemoryEfficientBSpline: out[b,o,p] = sum_i sum_g hat_g(nx[b,i,p]) * coef[b,o,i,g]
// hat_g(nx) = max(0, 1 - |nx - g|), nx = (clamp(x,-1,1)+1)*2.5 in [0,5], G=6.
// GEMM via mfma_f32_16x16x32_f16: A = hat-weights (p x k), B = coef (k x o).
// R5: MLP-first design. Each wave loads its WHOLE x-tile (12 dwordx4/lane,
// 192B/lane in flight) up front, transposes via a wave-PRIVATE LDS slice
// (no __syncthreads anywhere), computes 2 K-chunks back-to-back. cpre (f16,
// hw-k-order, 384KB) is L2-resident; bf waits never block on x completion
// because x loads are issued first (vmcnt is ordered).

typedef __fp16 half8_t __attribute__((ext_vector_type(8)));
typedef __fp16 half2_t __attribute__((ext_vector_type(2)));
typedef float f32x4 __attribute__((ext_vector_type(4)));
typedef float f32x2 __attribute__((ext_vector_type(2)));

#define NBATCH 8
#define OD 64
#define ID 64
#define PIX 36864          // 192*192
#define NG 6
#define PT 192             // pixels per block tile (48 per wave)
#define KI 32              // i per chunk
#define KROW 384           // k extent per (b,o) row in cpre
#define PTILES (PIX / PT)  // 192
#define LS 50              // LDS row stride (dwords): 8*50 % 32 = 16 -> 2-way reads (free)

#define CPRE_BYTES (NBATCH * OD * KROW * 2)  // 393216

__global__ __launch_bounds__(256)
void prep_coef(const float* __restrict__ coef, __fp16* __restrict__ cpre) {
  int idx = blockIdx.x * 256 + threadIdx.x;  // 0 .. 196607
  int b = idx / (OD * KROW);
  int rem = idx % (OD * KROW);
  int o = rem / KROW;
  int k = rem % KROW;
  int c = k / 192;
  int s = k % 192;
  int g = s >> 5;          // slot s = ks*32 + iof  <->  g = ks, iof = s&31
  int iof = s & 31;
  float v = coef[((size_t)(b * OD + o) * ID + c * KI + iof) * NG + g];
  cpre[idx] = (__fp16)v;   // writes coalesced
}

__global__ __launch_bounds__(256, 3)
void kan_mfma5(const float* __restrict__ x, const __fp16* __restrict__ cpre,
               float* __restrict__ out) {
  const int t = threadIdx.x;
  const int lane = t & 63;
  const int wave = t >> 6;   // p sub-range [wave*48, wave*48+48)
  const int q8 = lane >> 4;
  const int col = lane & 15;

  const int b = blockIdx.x / PTILES;
  const int pw = (blockIdx.x % PTILES) * PT + wave * 48;

  // wave-private transpose buffer: 32 i-rows x 48 p (stride 50) = 6.4KB/wave
  __shared__ float lds_all[4][KI * LS];
  float* __restrict__ nxs = lds_all[wave];

  // per-lane staging slots: unit u = j*64 + lane -> i-row u/12, p-col-x4 u%12
  int li[6], lpc[6];
#pragma unroll
  for (int j = 0; j < 6; ++j) {
    int u = j * 64 + lane;
    li[j] = u / 12;
    lpc[j] = u % 12;
  }

  const float* xb = x + (size_t)b * ID * PIX + pw;

  // ---- issue ALL x loads up front: 12 dwordx4/lane = 192B/lane in flight ----
  f32x4 xr0[6], xr1[6];
#pragma unroll
  for (int j = 0; j < 6; ++j)
    xr0[j] = *(const f32x4*)(xb + (size_t)li[j] * PIX + lpc[j] * 4);
#pragma unroll
  for (int j = 0; j < 6; ++j)
    xr1[j] = *(const f32x4*)(xb + (size_t)(KI + li[j]) * PIX + lpc[j] * 4);

  f32x4 acc[4][3];  // [ot][pti]
#pragma unroll
  for (int i = 0; i < 4; ++i)
#pragma unroll
    for (int j = 0; j < 3; ++j)
      acc[i][j] = (f32x4){0.f, 0.f, 0.f, 0.f};

  const __fp16* cb = cpre + (size_t)b * OD * KROW + q8 * 8;

#pragma unroll
  for (int c = 0; c < 2; ++c) {
    // ---- transform + stage this chunk (wave-private; no barrier) ----
#pragma unroll
    for (int j = 0; j < 6; ++j) {
      f32x4 v = (c == 0) ? xr0[j] : xr1[j];
      f32x4 n;
#pragma unroll
      for (int r = 0; r < 4; ++r) {
        float xv = fminf(fmaxf(v[r], -1.f), 1.f);
        n[r] = (xv + 1.f) * 2.5f;
      }
      int base = li[j] * LS + lpc[j] * 4;
      *(f32x2*)&nxs[base] = (f32x2){n[0], n[1]};
      *(f32x2*)&nxs[base + 2] = (f32x2){n[2], n[3]};
    }

    // ---- fragment-order reads (2-way bank aliasing = free) ----
    float nxv[3][8];
#pragma unroll
    for (int pti = 0; pti < 3; ++pti)
#pragma unroll
      for (int j = 0; j < 8; ++j)
        nxv[pti][j] = nxs[(q8 * 8 + j) * LS + pti * 16 + col];

    const __fp16* cc = cb + c * 192;
#pragma unroll
    for (int ks = 0; ks < 6; ++ks) {  // g = ks
      half8_t bf[4];  // B-frag: coef[k = ks*32 + q8*8 + j][o = ot*16 + col]
#pragma unroll
      for (int ot = 0; ot < 4; ++ot)
        bf[ot] = *(const half8_t*)(cc + (size_t)(ot * 16 + col) * KROW + ks * 32);

      const float gf = (float)ks;
#pragma unroll
      for (int pti = 0; pti < 3; ++pti) {
        union { half2_t h2[4]; half8_t v; } au;  // A-frag: hat weights at my p
#pragma unroll
        for (int jj = 0; jj < 4; ++jj) {
          float h0 = fmaxf(0.f, 1.f - fabsf(nxv[pti][2 * jj] - gf));
          float h1 = fmaxf(0.f, 1.f - fabsf(nxv[pti][2 * jj + 1] - gf));
          au.h2[jj] = __builtin_amdgcn_cvt_pkrtz(h0, h1);
        }
#pragma unroll
        for (int ot = 0; ot < 4; ++ot)
          acc[ot][pti] = __builtin_amdgcn_mfma_f32_16x16x32_f16(
              au.v, bf[ot], acc[ot][pti], 0, 0, 0);
      }
    }
  }

  // ---- epilogue: D row = p, col = o; 4 consecutive p per lane -> dwordx4 ----
  float* ob = out + (size_t)b * OD * PIX + pw + q8 * 4;
#pragma unroll
  for (int ot = 0; ot < 4; ++ot)
#pragma unroll
    for (int pti = 0; pti < 3; ++pti)
      *(f32x4*)(ob + (size_t)(ot * 16 + col) * PIX + pti * 16) = acc[ot][pti];
}

// ---------- fallback (proven R2 kernel) if ws too small for cpre ----------
#define AROW 104
#define XROW 18
__global__ __launch_bounds__(256, 2)
void kan_mfma_fb(const float* __restrict__ x, const float* __restrict__ coef,
                 float* __restrict__ out) {
  const int t = threadIdx.x;
  const int lane = t & 63;
  const int wave = t >> 6;
  const int q8 = lane >> 4;
  const int col = lane & 15;
  const int bid = blockIdx.x;
  const int b = bid / PTILES;
  const int p0 = (bid % PTILES) * PT;

  __shared__ __fp16 A_lds[OD][AROW] __attribute__((aligned(16)));
  __shared__ float nxf[PT][XROW] __attribute__((aligned(16)));

  f32x4 acc[4][3];
#pragma unroll
  for (int i = 0; i < 4; ++i)
#pragma unroll
    for (int j = 0; j < 3; ++j) acc[i][j] = (f32x4){0.f, 0.f, 0.f, 0.f};

  const float* xb = x + (size_t)b * ID * PIX + p0;
  const float* cb = coef + (size_t)b * OD * ID * NG;
  const int iof0 = (q8 & 1) * 8;
  const int ghalf = q8 >> 1;

  for (int c = 0; c < 4; ++c) {
    const int i0 = c * 16;
    __syncthreads();
#pragma unroll
    for (int j = 0; j < 12; ++j) {
      int lin = j * 256 + t;
      int p = lin % PT;
      int iof = lin / PT;
      float xvv = xb[(size_t)(i0 + iof) * PIX + p];
      xvv = fminf(fmaxf(xvv, -1.f), 1.f);
      nxf[p][iof] = (xvv + 1.f) * 2.5f;
    }
    {
      const int o = t >> 2;
      const int r0 = (t & 3) * 24;
      const float* crow = cb + o * (ID * NG) + i0 * NG + r0;
#pragma unroll
      for (int j = 0; j < 24; ++j) {
        int r = r0 + j;
        int iof = r / 6;
        int g = r - iof * 6;
        A_lds[o][g * 16 + iof] = (__fp16)crow[j];
      }
    }
    __syncthreads();

    float nxv[3][8];
#pragma unroll
    for (int pti = 0; pti < 3; ++pti) {
      int p = wave * 48 + pti * 16 + col;
#pragma unroll
      for (int j = 0; j < 8; ++j) nxv[pti][j] = nxf[p][iof0 + j];
    }
#pragma unroll
    for (int ks = 0; ks < 3; ++ks) {
      half8_t af[4];
#pragma unroll
      for (int ot = 0; ot < 4; ++ot)
        af[ot] = *(const half8_t*)&A_lds[ot * 16 + col][ks * 32 + q8 * 8];
      const float gf = (float)(2 * ks + ghalf);
#pragma unroll
      for (int pti = 0; pti < 3; ++pti) {
        union { half2_t h2[4]; half8_t v; } bu;
#pragma unroll
        for (int jj = 0; jj < 4; ++jj) {
          float h0 = fmaxf(0.f, 1.f - fabsf(nxv[pti][2 * jj] - gf));
          float h1 = fmaxf(0.f, 1.f - fabsf(nxv[pti][2 * jj + 1] - gf));
          bu.h2[jj] = __builtin_amdgcn_cvt_pkrtz(h0, h1);
        }
#pragma unroll
        for (int ot = 0; ot < 4; ++ot)
          acc[ot][pti] = __builtin_amdgcn_mfma_f32_16x16x32_f16(
              af[ot], bu.v, acc[ot][pti], 0, 0, 0);
      }
    }
  }
  float* ob = out + (size_t)b * OD * PIX + p0;
#pragma unroll
  for (int ot = 0; ot < 4; ++ot)
#pragma unroll
    for (int pti = 0; pti < 3; ++pti) {
      int p = wave * 48 + pti * 16 + col;
#pragma unroll
      for (int r = 0; r < 4; ++r)
        ob[(size_t)(ot * 16 + q8 * 4 + r) * PIX + p] = acc[ot][pti][r];
    }
}

extern "C" void kernel_launch(void* const* d_in, const int* in_sizes, int n_in,
                              void* d_out, int out_size, void* d_ws, size_t ws_size,
                              hipStream_t stream) {
  const float* x = (const float*)d_in[0];
  const float* coef = (const float*)d_in[1];
  float* out = (float*)d_out;
  if (ws_size >= (size_t)CPRE_BYTES) {
    __fp16* cpre = (__fp16*)d_ws;
    hipLaunchKernelGGL(prep_coef, dim3((NBATCH * OD * KROW) / 256), dim3(256), 0,
                       stream, coef, cpre);
    hipLaunchKernelGGL(kan_mfma5, dim3(NBATCH * PTILES), dim3(256), 0, stream, x,
                       cpre, out);
  } else {
    hipLaunchKernelGGL(kan_mfma_fb, dim3(NBATCH * PTILES), dim3(256), 0, stream,
                       x, coef, out);
  }
}